// Round 3
// baseline (404.689 us; speedup 1.0000x reference)
//
#include <hip/hip_runtime.h>
#include <math.h>

#define SEQ 4096
#define DMODEL 1024
#define NHEADS 16
#define HDIM 64

typedef __bf16 v8bf __attribute__((ext_vector_type(8)));
typedef float f32x4 __attribute__((ext_vector_type(4)));
typedef float f32x16 __attribute__((ext_vector_type(16)));
typedef int i32x2 __attribute__((ext_vector_type(2)));
typedef int i32x4 __attribute__((ext_vector_type(4)));

#define NPART 4608   // partial chunks (qb>=32): 16 heads * 288
#define SCALE_Q 0.18033688011112042f   // 0.125 * log2(e), folded into Q at proj

__device__ __forceinline__ unsigned short f2bf(float f) {
    union { float f; unsigned int u; } v; v.f = f;
    unsigned int u = v.u;
    return (unsigned short)((u + 0x7fffu + ((u >> 16) & 1u)) >> 16);
}

__device__ __forceinline__ int cvtpk(float lo, float hi) {
    int r;
    asm("v_cvt_pk_bf16_f32 %0, %1, %2" : "=v"(r) : "v"(lo), "v"(hi));
    return r;
}

// ---------------------------------------------------------------------------
// Kernel 1: projection GEMM  C = X @ W^T, bf16 MFMA.
//   z=0: qh[h][s][64] bf16, RoPE'd, PRE-SCALED by 0.125*log2(e)
//   z=1: kh[h][s][64] bf16, RoPE'd
//   z=2: vht[h][64][s] bf16 transposed
// ---------------------------------------------------------------------------
__global__ __launch_bounds__(256) void proj_rope_kernel(
    const float* __restrict__ Xq, const float* __restrict__ Xk, const float* __restrict__ Xv,
    const float* __restrict__ Wq, const float* __restrict__ Wk, const float* __restrict__ Wv,
    unsigned short* __restrict__ qh, unsigned short* __restrict__ kh,
    unsigned short* __restrict__ vht)
{
    const int tz = blockIdx.z;
    const float* __restrict__ X = (tz == 0) ? Xq : (tz == 1) ? Xk : Xv;
    const float* __restrict__ W = (tz == 0) ? Wq : (tz == 1) ? Wk : Wv;

    const int tid = threadIdx.x;
    const int lane = tid & 63;
    const int wid = tid >> 6;
    const int l15 = lane & 15;
    const int l4 = lane >> 4;
    const int wr = wid >> 1, wc = wid & 1;

    const int m0 = blockIdx.x * 128;
    const int n0 = blockIdx.y * 128;

    __shared__ __align__(16) unsigned short Ab[128 * 32];
    __shared__ __align__(16) unsigned short Bb[128 * 32];

    float4 ra[4], rb[4];
    f32x4 acc[4][4] = {};

    #pragma unroll
    for (int c = 0; c < 4; ++c) {
        int i = tid + (c << 8);
        int row = i >> 3;
        int c4 = (i & 7) << 2;
        ra[c] = *reinterpret_cast<const float4*>(X + (size_t)(m0 + row) * DMODEL + c4);
        rb[c] = *reinterpret_cast<const float4*>(W + (size_t)(n0 + row) * DMODEL + c4);
    }

    for (int kt = 0; kt < 32; ++kt) {
        if (kt > 0) __syncthreads();
        #pragma unroll
        for (int c = 0; c < 4; ++c) {
            int i = tid + (c << 8);
            int row = i >> 3;
            int c4 = (i & 7) << 2;
            int byte = row * 64 + (((c4 >> 3) ^ ((row >> 1) & 3)) << 4) + ((c4 << 1) & 15);
            uint2 pa, pb;
            pa.x = (unsigned)f2bf(ra[c].x) | ((unsigned)f2bf(ra[c].y) << 16);
            pa.y = (unsigned)f2bf(ra[c].z) | ((unsigned)f2bf(ra[c].w) << 16);
            pb.x = (unsigned)f2bf(rb[c].x) | ((unsigned)f2bf(rb[c].y) << 16);
            pb.y = (unsigned)f2bf(rb[c].z) | ((unsigned)f2bf(rb[c].w) << 16);
            *reinterpret_cast<uint2*>(reinterpret_cast<char*>(Ab) + byte) = pa;
            *reinterpret_cast<uint2*>(reinterpret_cast<char*>(Bb) + byte) = pb;
        }
        if (kt < 31) {
            int k0 = (kt + 1) << 5;
            #pragma unroll
            for (int c = 0; c < 4; ++c) {
                int i = tid + (c << 8);
                int row = i >> 3;
                int c4 = (i & 7) << 2;
                ra[c] = *reinterpret_cast<const float4*>(X + (size_t)(m0 + row) * DMODEL + k0 + c4);
                rb[c] = *reinterpret_cast<const float4*>(W + (size_t)(n0 + row) * DMODEL + k0 + c4);
            }
        }
        __syncthreads();

        v8bf af[4], bfr[4];
        #pragma unroll
        for (int mi = 0; mi < 4; ++mi) {
            int row = wr * 64 + mi * 16 + l15;
            int byte = row * 64 + ((l4 ^ ((row >> 1) & 3)) << 4);
            af[mi] = *reinterpret_cast<const v8bf*>(reinterpret_cast<const char*>(Ab) + byte);
        }
        #pragma unroll
        for (int ni = 0; ni < 4; ++ni) {
            int row = wc * 64 + ni * 16 + l15;
            int byte = row * 64 + ((l4 ^ ((row >> 1) & 3)) << 4);
            bfr[ni] = *reinterpret_cast<const v8bf*>(reinterpret_cast<const char*>(Bb) + byte);
        }
        #pragma unroll
        for (int mi = 0; mi < 4; ++mi)
            #pragma unroll
            for (int ni = 0; ni < 4; ++ni)
                acc[mi][ni] = __builtin_amdgcn_mfma_f32_16x16x32_bf16(af[mi], bfr[ni], acc[mi][ni], 0, 0, 0);
    }

    const int h = (n0 >> 6) + wc;
    const int mbase = m0 + wr * 64;
    if (tz == 2) {
        unsigned short* base = vht + (size_t)h * HDIM * SEQ;
        #pragma unroll
        for (int mi = 0; mi < 4; ++mi) {
            #pragma unroll
            for (int ni = 0; ni < 4; ++ni) {
                int d = ni * 16 + l15;
                int m = mbase + mi * 16 + l4 * 4;
                uint2 pk;
                pk.x = (unsigned)f2bf(acc[mi][ni][0]) | ((unsigned)f2bf(acc[mi][ni][1]) << 16);
                pk.y = (unsigned)f2bf(acc[mi][ni][2]) | ((unsigned)f2bf(acc[mi][ni][3]) << 16);
                *reinterpret_cast<uint2*>(base + (size_t)d * SEQ + m) = pk;
            }
        }
    } else {
        unsigned short* base = ((tz == 0) ? qh : kh) + (size_t)h * SEQ * HDIM;
        const float scl = (tz == 0) ? SCALE_Q : 1.0f;   // fold softmax scale into Q
        #pragma unroll
        for (int ni = 0; ni < 2; ++ni) {
            int j = ni * 16 + l15;
            float invf = expf(-(float)j * 0.28782313662425574f);  // ln(10000)/32
            #pragma unroll
            for (int mi = 0; mi < 4; ++mi) {
                #pragma unroll
                for (int r = 0; r < 4; ++r) {
                    int m = mbase + mi * 16 + l4 * 4 + r;
                    float ang = (float)m * invf;
                    float sn, cs;
                    sincosf(ang, &sn, &cs);
                    sn *= scl; cs *= scl;
                    float x1 = acc[mi][ni][r];
                    float x2 = acc[mi][ni + 2][r];
                    base[(size_t)m * HDIM + j]      = f2bf(x1 * cs - x2 * sn);
                    base[(size_t)m * HDIM + j + 32] = f2bf(x1 * sn + x2 * cs);
                }
            }
        }
    }
}

// ---------------------------------------------------------------------------
// Kernel 2: causal flash attention, swapped-QK^T 32x32, flash-decoding split.
// 1 wave/block, 32 q-rows, KV chunk of <=16 rounds (1024 kv) per wave.
// 5120 balanced waves. qb<32 (single chunk): write out directly.
// qb>=32: write bf16 unnormalized O^T partial + (m,l) -> combine kernel.
// Mask only diagonal round; defer-max (THR=8); scale pre-folded into Q.
// ---------------------------------------------------------------------------
__global__ __launch_bounds__(64, 4) void attn_kernel(
    const unsigned short* __restrict__ qh, const unsigned short* __restrict__ kh,
    const unsigned short* __restrict__ vht, float* __restrict__ out,
    unsigned short* __restrict__ po, float* __restrict__ ml)
{
    const int lane = threadIdx.x & 63;
    const int l31 = lane & 31;
    const int l5 = lane >> 5;

    const int bid = blockIdx.x;
    const int h = bid & 15;                  // bid%8 XCD sees heads {x, x+8}
    const int r = bid >> 4;                  // 0..319 per head
    int qb, c, nc;
    if (r < 32)       { qb = r;                     c = 0;            nc = 1; }
    else if (r < 96)  { qb = 32 + ((r - 32) >> 1);  c = (r - 32) & 1; nc = 2; }
    else if (r < 192) { int rr = r - 96; qb = 64 + rr / 3; c = rr - (qb - 64) * 3; nc = 3; }
    else              { int rr = r - 192; qb = 96 + (rr >> 2); c = rr & 3; nc = 4; }

    const int q0 = qb * 32;
    const int q = q0 + l31;
    const int nt = (q0 + 32 + 63) >> 6;      // total kv-rounds for this q-tile
    const int t0 = c * 16;
    const int t1 = min(t0 + 16, nt);

    const unsigned short* __restrict__ qbase = qh + ((size_t)h * SEQ + q) * HDIM + l5 * 8;
    const unsigned short* __restrict__ kbase = kh + ((size_t)h * SEQ + l31) * HDIM + l5 * 8;
    const unsigned short* __restrict__ vbase = vht + ((size_t)h * HDIM + l31) * SEQ + l5 * 8;

    v8bf qf[4];
    #pragma unroll
    for (int dk = 0; dk < 4; ++dk)
        qf[dk] = *reinterpret_cast<const v8bf*>(qbase + dk * 16);

    f32x16 of[2] = {};
    float mreg = -INFINITY, lreg = 0.0f;

    auto LOADK = [&](v8bf (&KB)[8], int T) {
        const unsigned short* kp = kbase + (size_t)T * 64 * HDIM;
        #pragma unroll
        for (int ns = 0; ns < 2; ++ns)
            #pragma unroll
            for (int dk = 0; dk < 4; ++dk)
                KB[ns * 4 + dk] = *reinterpret_cast<const v8bf*>(kp + ns * 32 * HDIM + dk * 16);
    };

    auto ROUND = [&](int T, v8bf (&KC)[8], v8bf (&KN)[8]) {
        const int kv0 = T * 64;
        // V^T A-fragments (issued early, consumed after softmax)
        v8bf vf[8];
        #pragma unroll
        for (int dt = 0; dt < 2; ++dt)
            #pragma unroll
            for (int kb = 0; kb < 4; ++kb)
                vf[dt * 4 + kb] = *reinterpret_cast<const v8bf*>(
                    vbase + (size_t)dt * 32 * SEQ + kv0 + kb * 16);
        if (T + 1 < t1) LOADK(KN, T + 1);

        // S^T = K Q^T : col=q=l31, row_kv = kv0 + 32ns + (i&3)+8*(i>>2)+4*l5
        f32x16 st[2];
        #pragma unroll
        for (int ns = 0; ns < 2; ++ns) {
            f32x16 acc = {};
            #pragma unroll
            for (int dk = 0; dk < 4; ++dk)
                acc = __builtin_amdgcn_mfma_f32_32x32x16_bf16(KC[ns * 4 + dk], qf[dk], acc, 0, 0, 0);
            st[ns] = acc;
        }

        // causal mask: provably needed only on the globally-last round
        if (T == nt - 1) {
            const int kvb = kv0 + 4 * l5;
            #pragma unroll
            for (int ns = 0; ns < 2; ++ns)
                #pragma unroll
                for (int i = 0; i < 16; ++i) {
                    int kv = kvb + ns * 32 + (i & 3) + 8 * (i >> 2);
                    if (kv > q) st[ns][i] = -INFINITY;
                }
        }

        // row max: in-lane tree + 1 permlane32_swap
        float t16[16];
        #pragma unroll
        for (int i = 0; i < 16; ++i) t16[i] = fmaxf(st[0][i], st[1][i]);
        #pragma unroll
        for (int i = 0; i < 8; ++i) t16[i] = fmaxf(t16[i], t16[i + 8]);
        #pragma unroll
        for (int i = 0; i < 4; ++i) t16[i] = fmaxf(t16[i], t16[i + 4]);
        float pmax = fmaxf(fmaxf(t16[0], t16[1]), fmaxf(t16[2], t16[3]));
        {
            i32x2 sw = __builtin_amdgcn_permlane32_swap(__float_as_int(pmax), __float_as_int(pmax), false, false);
            pmax = fmaxf(__int_as_float(sw.x), __int_as_float(sw.y));
        }

        // defer-max (T13): rescale only if max grew by > 8 (exp2 domain)
        if (!__all(pmax - mreg <= 8.0f)) {
            float mnew = fmaxf(mreg, pmax);
            float sc = exp2f(mreg - mnew);
            lreg *= sc;
            #pragma unroll
            for (int dt = 0; dt < 2; ++dt)
                #pragma unroll
                for (int i = 0; i < 16; ++i) of[dt][i] *= sc;
            mreg = mnew;
        }

        // exp2 + partial row-sum
        float ps0 = 0.f, ps1 = 0.f, ps2 = 0.f, ps3 = 0.f;
        #pragma unroll
        for (int ns = 0; ns < 2; ++ns)
            #pragma unroll
            for (int i = 0; i < 16; ++i) {
                float p = exp2f(st[ns][i] - mreg);
                st[ns][i] = p;
                if ((i & 3) == 0) ps0 += p; else if ((i & 3) == 1) ps1 += p;
                else if ((i & 3) == 2) ps2 += p; else ps3 += p;
            }
        lreg += (ps0 + ps1) + (ps2 + ps3);

        // P^T B-fragments: cvt_pk + permlane32_swap (T12)
        v8bf pt[4];
        #pragma unroll
        for (int kb = 0; kb < 4; ++kb) {
            int ns = kb >> 1, kp = (kb & 1) * 8;
            int A0 = cvtpk(st[ns][kp + 0], st[ns][kp + 1]);
            int A1 = cvtpk(st[ns][kp + 2], st[ns][kp + 3]);
            int B0 = cvtpk(st[ns][kp + 4], st[ns][kp + 5]);
            int B1 = cvtpk(st[ns][kp + 6], st[ns][kp + 7]);
            i32x2 s0 = __builtin_amdgcn_permlane32_swap(A0, B0, false, false);
            i32x2 s1 = __builtin_amdgcn_permlane32_swap(A1, B1, false, false);
            i32x4 u; u.x = s0.x; u.y = s1.x; u.z = s0.y; u.w = s1.y;
            v8bf p; __builtin_memcpy(&p, &u, 16);
            pt[kb] = p;
        }

        // O^T += V^T P^T
        #pragma unroll
        for (int dt = 0; dt < 2; ++dt)
            #pragma unroll
            for (int kb = 0; kb < 4; ++kb)
                of[dt] = __builtin_amdgcn_mfma_f32_32x32x16_bf16(vf[dt * 4 + kb], pt[kb], of[dt], 0, 0, 0);
    };

    v8bf kA[8], kB[8];
    LOADK(kA, t0);
    int t = t0;
    while (true) {
        ROUND(t, kA, kB);
        if (++t == t1) break;
        ROUND(t, kB, kA);
        if (++t == t1) break;
    }

    // pair-sum l across halves (both halves end with full row-sum)
    {
        i32x2 sw = __builtin_amdgcn_permlane32_swap(__float_as_int(lreg), __float_as_int(lreg), false, false);
        lreg = __int_as_float(sw.x) + __int_as_float(sw.y);
    }

    if (nc == 1) {
        float inv = 1.0f / lreg;
        float* obase = out + (size_t)q * DMODEL + h * HDIM + l5 * 4;
        #pragma unroll
        for (int dt = 0; dt < 2; ++dt)
            #pragma unroll
            for (int g = 0; g < 4; ++g) {
                f32x4 o4;
                o4[0] = of[dt][g * 4 + 0] * inv;
                o4[1] = of[dt][g * 4 + 1] * inv;
                o4[2] = of[dt][g * 4 + 2] * inv;
                o4[3] = of[dt][g * 4 + 3] * inv;
                *reinterpret_cast<f32x4*>(obase + dt * 32 + g * 8) = o4;
            }
    } else {
        const int p = h * 288 + (r - 32);
        unsigned short* pb = po + ((size_t)p * 32 + l31) * 64 + l5 * 4;
        #pragma unroll
        for (int dt = 0; dt < 2; ++dt)
            #pragma unroll
            for (int g = 0; g < 4; ++g) {
                uint2 u;
                u.x = (unsigned)cvtpk(of[dt][g * 4 + 0], of[dt][g * 4 + 1]);
                u.y = (unsigned)cvtpk(of[dt][g * 4 + 2], of[dt][g * 4 + 3]);
                *reinterpret_cast<uint2*>(pb + dt * 32 + g * 8) = u;
            }
        if (l5 == 0) {
            float2 v; v.x = mreg; v.y = lreg;
            reinterpret_cast<float2*>(ml)[(size_t)p * 32 + l31] = v;
        }
    }
}

// ---------------------------------------------------------------------------
// Kernel 3: combine partials for qb>=32 (2..4 chunks per q-tile).
// 1536 blocks x 64 threads; lane = head-dim d; loop 32 q-rows.
// ---------------------------------------------------------------------------
__global__ __launch_bounds__(64) void combine_kernel(
    const unsigned short* __restrict__ po, const float* __restrict__ ml,
    float* __restrict__ out)
{
    const int b = blockIdx.x;
    const int h = b / 96;
    const int j = b - h * 96;
    const int qb = 32 + j;
    int nc, r0;
    if (qb < 64)      { nc = 2; r0 = 32 + ((qb - 32) << 1); }
    else if (qb < 96) { nc = 3; r0 = 96 + (qb - 64) * 3; }
    else              { nc = 4; r0 = 192 + ((qb - 96) << 2); }
    const int p0 = h * 288 + (r0 - 32);
    const int d = threadIdx.x;
    const int q0 = qb * 32;

    for (int row = 0; row < 32; ++row) {
        float mc[4], lc[4];
        float M = -INFINITY;
        #pragma unroll
        for (int ci = 0; ci < 4; ++ci)
            if (ci < nc) {
                float2 v = reinterpret_cast<const float2*>(ml)[(size_t)(p0 + ci) * 32 + row];
                mc[ci] = v.x; lc[ci] = v.y;
                M = fmaxf(M, v.x);
            }
        float L = 0.0f, O = 0.0f;
        #pragma unroll
        for (int ci = 0; ci < 4; ++ci)
            if (ci < nc) {
                float w = exp2f(mc[ci] - M);
                L += lc[ci] * w;
                unsigned int raw = po[((size_t)(p0 + ci) * 32 + row) * 64 + d];
                union { unsigned int u; float f; } cv; cv.u = raw << 16;
                O += cv.f * w;
            }
        out[(size_t)(q0 + row) * DMODEL + h * HDIM + d] = O / L;
    }
}

extern "C" void kernel_launch(void* const* d_in, const int* in_sizes, int n_in,
                              void* d_out, int out_size, void* d_ws, size_t ws_size,
                              hipStream_t stream) {
    (void)in_sizes; (void)n_in; (void)out_size; (void)ws_size;
    const float* q  = (const float*)d_in[0];
    const float* k  = (const float*)d_in[1];
    const float* v  = (const float*)d_in[2];
    // d_in[3] = mask: tril(ones) -> causal, applied analytically
    const float* Wq = (const float*)d_in[4];
    const float* Wk = (const float*)d_in[5];
    const float* Wv = (const float*)d_in[6];

    unsigned short* qh  = (unsigned short*)d_ws;                      // 8.4 MB
    unsigned short* kh  = qh + (size_t)NHEADS * SEQ * HDIM;           // 8.4 MB
    unsigned short* vht = kh + (size_t)NHEADS * SEQ * HDIM;           // 8.4 MB
    unsigned short* po  = vht + (size_t)NHEADS * SEQ * HDIM;          // 18.9 MB
    float* ml = (float*)(po + (size_t)NPART * 32 * 64);               // 1.2 MB
    float* out = (float*)d_out;

    dim3 g1(SEQ / 128, DMODEL / 128, 3);
    proj_rope_kernel<<<g1, 256, 0, stream>>>(q, k, v, Wq, Wk, Wv, qh, kh, vht);

    attn_kernel<<<dim3(16 * 320), 64, 0, stream>>>(qh, kh, vht, out, po, ml);

    combine_kernel<<<dim3(16 * 96), 64, 0, stream>>>(po, ml, out);
}

// Round 4
// 242.388 us; speedup vs baseline: 1.6696x; 1.6696x over previous
//
#include <hip/hip_runtime.h>
#include <math.h>

#define SEQ 4096
#define DMODEL 1024
#define NHEADS 16
#define HDIM 64

typedef __bf16 v8bf __attribute__((ext_vector_type(8)));
typedef float f32x4 __attribute__((ext_vector_type(4)));
typedef float f32x16 __attribute__((ext_vector_type(16)));
typedef int i32x2 __attribute__((ext_vector_type(2)));
typedef int i32x4 __attribute__((ext_vector_type(4)));

#define NPART 4608   // partial chunks (qb>=32): 16 heads * 288
#define SCALE_Q 0.18033688011112042f   // 0.125 * log2(e), folded into Q at proj

__device__ __forceinline__ unsigned short f2bf(float f) {
    union { float f; unsigned int u; } v; v.f = f;
    unsigned int u = v.u;
    return (unsigned short)((u + 0x7fffu + ((u >> 16) & 1u)) >> 16);
}

__device__ __forceinline__ int cvtpk(float lo, float hi) {
    int r;
    asm("v_cvt_pk_bf16_f32 %0, %1, %2" : "=v"(r) : "v"(lo), "v"(hi));
    return r;
}

// ---------------------------------------------------------------------------
// Kernel 1: projection GEMM  C = X @ W^T, bf16 MFMA.
//   z=0: qh[h][s][64] bf16, RoPE'd, PRE-SCALED by 0.125*log2(e)
//   z=1: kh[h][s][64] bf16, RoPE'd
//   z=2: vht[h][64][s] bf16 transposed
// ---------------------------------------------------------------------------
__global__ __launch_bounds__(256) void proj_rope_kernel(
    const float* __restrict__ Xq, const float* __restrict__ Xk, const float* __restrict__ Xv,
    const float* __restrict__ Wq, const float* __restrict__ Wk, const float* __restrict__ Wv,
    unsigned short* __restrict__ qh, unsigned short* __restrict__ kh,
    unsigned short* __restrict__ vht)
{
    const int tz = blockIdx.z;
    const float* __restrict__ X = (tz == 0) ? Xq : (tz == 1) ? Xk : Xv;
    const float* __restrict__ W = (tz == 0) ? Wq : (tz == 1) ? Wk : Wv;

    const int tid = threadIdx.x;
    const int lane = tid & 63;
    const int wid = tid >> 6;
    const int l15 = lane & 15;
    const int l4 = lane >> 4;
    const int wr = wid >> 1, wc = wid & 1;

    const int m0 = blockIdx.x * 128;
    const int n0 = blockIdx.y * 128;

    __shared__ __align__(16) unsigned short Ab[128 * 32];
    __shared__ __align__(16) unsigned short Bb[128 * 32];

    float4 ra[4], rb[4];
    f32x4 acc[4][4] = {};

    #pragma unroll
    for (int c = 0; c < 4; ++c) {
        int i = tid + (c << 8);
        int row = i >> 3;
        int c4 = (i & 7) << 2;
        ra[c] = *reinterpret_cast<const float4*>(X + (size_t)(m0 + row) * DMODEL + c4);
        rb[c] = *reinterpret_cast<const float4*>(W + (size_t)(n0 + row) * DMODEL + c4);
    }

    for (int kt = 0; kt < 32; ++kt) {
        if (kt > 0) __syncthreads();
        #pragma unroll
        for (int c = 0; c < 4; ++c) {
            int i = tid + (c << 8);
            int row = i >> 3;
            int c4 = (i & 7) << 2;
            int byte = row * 64 + (((c4 >> 3) ^ ((row >> 1) & 3)) << 4) + ((c4 << 1) & 15);
            uint2 pa, pb;
            pa.x = (unsigned)f2bf(ra[c].x) | ((unsigned)f2bf(ra[c].y) << 16);
            pa.y = (unsigned)f2bf(ra[c].z) | ((unsigned)f2bf(ra[c].w) << 16);
            pb.x = (unsigned)f2bf(rb[c].x) | ((unsigned)f2bf(rb[c].y) << 16);
            pb.y = (unsigned)f2bf(rb[c].z) | ((unsigned)f2bf(rb[c].w) << 16);
            *reinterpret_cast<uint2*>(reinterpret_cast<char*>(Ab) + byte) = pa;
            *reinterpret_cast<uint2*>(reinterpret_cast<char*>(Bb) + byte) = pb;
        }
        if (kt < 31) {
            int k0 = (kt + 1) << 5;
            #pragma unroll
            for (int c = 0; c < 4; ++c) {
                int i = tid + (c << 8);
                int row = i >> 3;
                int c4 = (i & 7) << 2;
                ra[c] = *reinterpret_cast<const float4*>(X + (size_t)(m0 + row) * DMODEL + k0 + c4);
                rb[c] = *reinterpret_cast<const float4*>(W + (size_t)(n0 + row) * DMODEL + k0 + c4);
            }
        }
        __syncthreads();

        v8bf af[4], bfr[4];
        #pragma unroll
        for (int mi = 0; mi < 4; ++mi) {
            int row = wr * 64 + mi * 16 + l15;
            int byte = row * 64 + ((l4 ^ ((row >> 1) & 3)) << 4);
            af[mi] = *reinterpret_cast<const v8bf*>(reinterpret_cast<const char*>(Ab) + byte);
        }
        #pragma unroll
        for (int ni = 0; ni < 4; ++ni) {
            int row = wc * 64 + ni * 16 + l15;
            int byte = row * 64 + ((l4 ^ ((row >> 1) & 3)) << 4);
            bfr[ni] = *reinterpret_cast<const v8bf*>(reinterpret_cast<const char*>(Bb) + byte);
        }
        #pragma unroll
        for (int mi = 0; mi < 4; ++mi)
            #pragma unroll
            for (int ni = 0; ni < 4; ++ni)
                acc[mi][ni] = __builtin_amdgcn_mfma_f32_16x16x32_bf16(af[mi], bfr[ni], acc[mi][ni], 0, 0, 0);
    }

    const int h = (n0 >> 6) + wc;
    const int mbase = m0 + wr * 64;
    if (tz == 2) {
        unsigned short* base = vht + (size_t)h * HDIM * SEQ;
        #pragma unroll
        for (int mi = 0; mi < 4; ++mi) {
            #pragma unroll
            for (int ni = 0; ni < 4; ++ni) {
                int d = ni * 16 + l15;
                int m = mbase + mi * 16 + l4 * 4;
                uint2 pk;
                pk.x = (unsigned)f2bf(acc[mi][ni][0]) | ((unsigned)f2bf(acc[mi][ni][1]) << 16);
                pk.y = (unsigned)f2bf(acc[mi][ni][2]) | ((unsigned)f2bf(acc[mi][ni][3]) << 16);
                *reinterpret_cast<uint2*>(base + (size_t)d * SEQ + m) = pk;
            }
        }
    } else {
        unsigned short* base = ((tz == 0) ? qh : kh) + (size_t)h * SEQ * HDIM;
        const float scl = (tz == 0) ? SCALE_Q : 1.0f;   // fold softmax scale into Q
        #pragma unroll
        for (int ni = 0; ni < 2; ++ni) {
            int j = ni * 16 + l15;
            float invf = expf(-(float)j * 0.28782313662425574f);  // ln(10000)/32
            #pragma unroll
            for (int mi = 0; mi < 4; ++mi) {
                #pragma unroll
                for (int r = 0; r < 4; ++r) {
                    int m = mbase + mi * 16 + l4 * 4 + r;
                    float ang = (float)m * invf;
                    float sn, cs;
                    sincosf(ang, &sn, &cs);
                    sn *= scl; cs *= scl;
                    float x1 = acc[mi][ni][r];
                    float x2 = acc[mi][ni + 2][r];
                    base[(size_t)m * HDIM + j]      = f2bf(x1 * cs - x2 * sn);
                    base[(size_t)m * HDIM + j + 32] = f2bf(x1 * sn + x2 * cs);
                }
            }
        }
    }
}

// ---------------------------------------------------------------------------
// Kernel 2: causal flash attention, swapped-QK^T 32x32, flash-decoding split.
// 1 wave/block, 32 q-rows, KV chunk of <=16 rounds (1024 kv) per wave.
// 5120 balanced waves. XCD-grouped heads (2/XCD -> K/V L2-resident), long
// chunks first. launch_bounds(64,2): round-2's proven no-spill codegen.
// qb<32 (single chunk): write out directly.
// qb>=32: bf16 unnormalized O^T partial + (m,l) -> combine kernel.
// ---------------------------------------------------------------------------
__global__ __launch_bounds__(64, 2) void attn_kernel(
    const unsigned short* __restrict__ qh, const unsigned short* __restrict__ kh,
    const unsigned short* __restrict__ vht, float* __restrict__ out,
    unsigned short* __restrict__ po, float* __restrict__ ml)
{
    const int lane = threadIdx.x & 63;
    const int l31 = lane & 31;
    const int l5 = lane >> 5;

    const int bid = blockIdx.x;
    const int xcd = bid & 7;                 // HW: consecutive bids round-robin XCDs
    const int idx = bid >> 3;                // 0..639 per XCD
    const int hsel = (idx >= 320) ? 1 : 0;
    const int h = (xcd << 1) | hsel;         // 2 heads per XCD -> K/V L2-resident
    const int r = 319 - (idx - hsel * 320);  // descending: long chunks first

    int qb, c, nc;
    if (r < 32)       { qb = r;                     c = 0;            nc = 1; }
    else if (r < 96)  { qb = 32 + ((r - 32) >> 1);  c = (r - 32) & 1; nc = 2; }
    else if (r < 192) { int rr = r - 96; qb = 64 + rr / 3; c = rr - (qb - 64) * 3; nc = 3; }
    else              { int rr = r - 192; qb = 96 + (rr >> 2); c = rr & 3; nc = 4; }

    const int q0 = qb * 32;
    const int q = q0 + l31;
    const int nt = (q0 + 32 + 63) >> 6;      // total kv-rounds for this q-tile
    const int t0 = c * 16;
    const int t1 = min(t0 + 16, nt);

    const unsigned short* __restrict__ qbase = qh + ((size_t)h * SEQ + q) * HDIM + l5 * 8;
    const unsigned short* __restrict__ kbase = kh + ((size_t)h * SEQ + l31) * HDIM + l5 * 8;
    const unsigned short* __restrict__ vbase = vht + ((size_t)h * HDIM + l31) * SEQ + l5 * 8;

    v8bf qf[4];
    #pragma unroll
    for (int dk = 0; dk < 4; ++dk)
        qf[dk] = *reinterpret_cast<const v8bf*>(qbase + dk * 16);

    f32x16 of[2] = {};
    float mreg = -INFINITY, lreg = 0.0f;

    auto LOADK = [&](v8bf (&KB)[8], int T) {
        const unsigned short* kp = kbase + (size_t)T * 64 * HDIM;
        #pragma unroll
        for (int ns = 0; ns < 2; ++ns)
            #pragma unroll
            for (int dk = 0; dk < 4; ++dk)
                KB[ns * 4 + dk] = *reinterpret_cast<const v8bf*>(kp + ns * 32 * HDIM + dk * 16);
    };

    auto ROUND = [&](int T, v8bf (&KC)[8], v8bf (&KN)[8]) {
        const int kv0 = T * 64;
        // V^T A-fragments (issued early, consumed after softmax)
        v8bf vf[8];
        #pragma unroll
        for (int dt = 0; dt < 2; ++dt)
            #pragma unroll
            for (int kb = 0; kb < 4; ++kb)
                vf[dt * 4 + kb] = *reinterpret_cast<const v8bf*>(
                    vbase + (size_t)dt * 32 * SEQ + kv0 + kb * 16);
        if (T + 1 < t1) LOADK(KN, T + 1);

        // S^T = K Q^T : col=q=l31, row_kv = kv0 + 32ns + (i&3)+8*(i>>2)+4*l5
        f32x16 st[2];
        #pragma unroll
        for (int ns = 0; ns < 2; ++ns) {
            f32x16 acc = {};
            #pragma unroll
            for (int dk = 0; dk < 4; ++dk)
                acc = __builtin_amdgcn_mfma_f32_32x32x16_bf16(KC[ns * 4 + dk], qf[dk], acc, 0, 0, 0);
            st[ns] = acc;
        }

        // causal mask: provably needed only on the globally-last round
        if (T == nt - 1) {
            const int kvb = kv0 + 4 * l5;
            #pragma unroll
            for (int ns = 0; ns < 2; ++ns)
                #pragma unroll
                for (int i = 0; i < 16; ++i) {
                    int kv = kvb + ns * 32 + (i & 3) + 8 * (i >> 2);
                    if (kv > q) st[ns][i] = -INFINITY;
                }
        }

        // row max: in-lane tree + 1 permlane32_swap
        float t16[16];
        #pragma unroll
        for (int i = 0; i < 16; ++i) t16[i] = fmaxf(st[0][i], st[1][i]);
        #pragma unroll
        for (int i = 0; i < 8; ++i) t16[i] = fmaxf(t16[i], t16[i + 8]);
        #pragma unroll
        for (int i = 0; i < 4; ++i) t16[i] = fmaxf(t16[i], t16[i + 4]);
        float pmax = fmaxf(fmaxf(t16[0], t16[1]), fmaxf(t16[2], t16[3]));
        {
            i32x2 sw = __builtin_amdgcn_permlane32_swap(__float_as_int(pmax), __float_as_int(pmax), false, false);
            pmax = fmaxf(__int_as_float(sw.x), __int_as_float(sw.y));
        }

        // defer-max (T13): rescale only if max grew by > 8 (exp2 domain)
        if (!__all(pmax - mreg <= 8.0f)) {
            float mnew = fmaxf(mreg, pmax);
            float sc = exp2f(mreg - mnew);
            lreg *= sc;
            #pragma unroll
            for (int dt = 0; dt < 2; ++dt)
                #pragma unroll
                for (int i = 0; i < 16; ++i) of[dt][i] *= sc;
            mreg = mnew;
        }

        // exp2 + partial row-sum
        float ps0 = 0.f, ps1 = 0.f, ps2 = 0.f, ps3 = 0.f;
        #pragma unroll
        for (int ns = 0; ns < 2; ++ns)
            #pragma unroll
            for (int i = 0; i < 16; ++i) {
                float p = exp2f(st[ns][i] - mreg);
                st[ns][i] = p;
                if ((i & 3) == 0) ps0 += p; else if ((i & 3) == 1) ps1 += p;
                else if ((i & 3) == 2) ps2 += p; else ps3 += p;
            }
        lreg += (ps0 + ps1) + (ps2 + ps3);

        // P^T B-fragments: cvt_pk + permlane32_swap (T12)
        v8bf pt[4];
        #pragma unroll
        for (int kb = 0; kb < 4; ++kb) {
            int ns = kb >> 1, kp = (kb & 1) * 8;
            int A0 = cvtpk(st[ns][kp + 0], st[ns][kp + 1]);
            int A1 = cvtpk(st[ns][kp + 2], st[ns][kp + 3]);
            int B0 = cvtpk(st[ns][kp + 4], st[ns][kp + 5]);
            int B1 = cvtpk(st[ns][kp + 6], st[ns][kp + 7]);
            i32x2 s0 = __builtin_amdgcn_permlane32_swap(A0, B0, false, false);
            i32x2 s1 = __builtin_amdgcn_permlane32_swap(A1, B1, false, false);
            i32x4 u; u.x = s0.x; u.y = s1.x; u.z = s0.y; u.w = s1.y;
            v8bf p; __builtin_memcpy(&p, &u, 16);
            pt[kb] = p;
        }

        // O^T += V^T P^T
        #pragma unroll
        for (int dt = 0; dt < 2; ++dt)
            #pragma unroll
            for (int kb = 0; kb < 4; ++kb)
                of[dt] = __builtin_amdgcn_mfma_f32_32x32x16_bf16(vf[dt * 4 + kb], pt[kb], of[dt], 0, 0, 0);
    };

    v8bf kA[8], kB[8];
    LOADK(kA, t0);
    int t = t0;
    while (true) {
        ROUND(t, kA, kB);
        if (++t == t1) break;
        ROUND(t, kB, kA);
        if (++t == t1) break;
    }

    // pair-sum l across halves (both halves end with full row-sum)
    {
        i32x2 sw = __builtin_amdgcn_permlane32_swap(__float_as_int(lreg), __float_as_int(lreg), false, false);
        lreg = __int_as_float(sw.x) + __int_as_float(sw.y);
    }

    if (nc == 1) {
        float inv = 1.0f / lreg;
        float* obase = out + (size_t)q * DMODEL + h * HDIM + l5 * 4;
        #pragma unroll
        for (int dt = 0; dt < 2; ++dt)
            #pragma unroll
            for (int g = 0; g < 4; ++g) {
                f32x4 o4;
                o4[0] = of[dt][g * 4 + 0] * inv;
                o4[1] = of[dt][g * 4 + 1] * inv;
                o4[2] = of[dt][g * 4 + 2] * inv;
                o4[3] = of[dt][g * 4 + 3] * inv;
                *reinterpret_cast<f32x4*>(obase + dt * 32 + g * 8) = o4;
            }
    } else {
        const int p = h * 288 + (r - 32);
        unsigned short* pb = po + ((size_t)p * 32 + l31) * 64 + l5 * 4;
        #pragma unroll
        for (int dt = 0; dt < 2; ++dt)
            #pragma unroll
            for (int g = 0; g < 4; ++g) {
                uint2 u;
                u.x = (unsigned)cvtpk(of[dt][g * 4 + 0], of[dt][g * 4 + 1]);
                u.y = (unsigned)cvtpk(of[dt][g * 4 + 2], of[dt][g * 4 + 3]);
                *reinterpret_cast<uint2*>(pb + dt * 32 + g * 8) = u;
            }
        if (l5 == 0) {
            float2 v; v.x = mreg; v.y = lreg;
            reinterpret_cast<float2*>(ml)[(size_t)p * 32 + l31] = v;
        }
    }
}

// ---------------------------------------------------------------------------
// Kernel 3: combine partials for qb>=32 (2..4 chunks per q-tile).
// 1536 blocks x 64 threads; lane = head-dim d; loop 32 q-rows.
// ---------------------------------------------------------------------------
__global__ __launch_bounds__(64) void combine_kernel(
    const unsigned short* __restrict__ po, const float* __restrict__ ml,
    float* __restrict__ out)
{
    const int b = blockIdx.x;
    const int h = b / 96;
    const int j = b - h * 96;
    const int qb = 32 + j;
    int nc, r0;
    if (qb < 64)      { nc = 2; r0 = 32 + ((qb - 32) << 1); }
    else if (qb < 96) { nc = 3; r0 = 96 + (qb - 64) * 3; }
    else              { nc = 4; r0 = 192 + ((qb - 96) << 2); }
    const int p0 = h * 288 + (r0 - 32);
    const int d = threadIdx.x;
    const int q0 = qb * 32;

    for (int row = 0; row < 32; ++row) {
        float mc[4], lc[4];
        float M = -INFINITY;
        #pragma unroll
        for (int ci = 0; ci < 4; ++ci)
            if (ci < nc) {
                float2 v = reinterpret_cast<const float2*>(ml)[(size_t)(p0 + ci) * 32 + row];
                mc[ci] = v.x; lc[ci] = v.y;
                M = fmaxf(M, v.x);
            }
        float L = 0.0f, O = 0.0f;
        #pragma unroll
        for (int ci = 0; ci < 4; ++ci)
            if (ci < nc) {
                float w = exp2f(mc[ci] - M);
                L += lc[ci] * w;
                unsigned int raw = po[((size_t)(p0 + ci) * 32 + row) * 64 + d];
                union { unsigned int u; float f; } cv; cv.u = raw << 16;
                O += cv.f * w;
            }
        out[(size_t)(q0 + row) * DMODEL + h * HDIM + d] = O / L;
    }
}

extern "C" void kernel_launch(void* const* d_in, const int* in_sizes, int n_in,
                              void* d_out, int out_size, void* d_ws, size_t ws_size,
                              hipStream_t stream) {
    (void)in_sizes; (void)n_in; (void)out_size; (void)ws_size;
    const float* q  = (const float*)d_in[0];
    const float* k  = (const float*)d_in[1];
    const float* v  = (const float*)d_in[2];
    // d_in[3] = mask: tril(ones) -> causal, applied analytically
    const float* Wq = (const float*)d_in[4];
    const float* Wk = (const float*)d_in[5];
    const float* Wv = (const float*)d_in[6];

    unsigned short* qh  = (unsigned short*)d_ws;                      // 8.4 MB
    unsigned short* kh  = qh + (size_t)NHEADS * SEQ * HDIM;           // 8.4 MB
    unsigned short* vht = kh + (size_t)NHEADS * SEQ * HDIM;           // 8.4 MB
    unsigned short* po  = vht + (size_t)NHEADS * SEQ * HDIM;          // 18.9 MB
    float* ml = (float*)(po + (size_t)NPART * 32 * 64);               // 1.2 MB
    float* out = (float*)d_out;

    dim3 g1(SEQ / 128, DMODEL / 128, 3);
    proj_rope_kernel<<<g1, 256, 0, stream>>>(q, k, v, Wq, Wk, Wv, qh, kh, vht);

    attn_kernel<<<dim3(16 * 320), 64, 0, stream>>>(qh, kh, vht, out, po, ml);

    combine_kernel<<<dim3(16 * 96), 64, 0, stream>>>(po, ml, out);
}

// Round 5
// 218.480 us; speedup vs baseline: 1.8523x; 1.1094x over previous
//
#include <hip/hip_runtime.h>
#include <math.h>

#define SEQ 4096
#define DMODEL 1024
#define NHEADS 16
#define HDIM 64

typedef __bf16 v8bf __attribute__((ext_vector_type(8)));
typedef float f32x4 __attribute__((ext_vector_type(4)));
typedef float f32x16 __attribute__((ext_vector_type(16)));
typedef int i32x2 __attribute__((ext_vector_type(2)));
typedef int i32x4 __attribute__((ext_vector_type(4)));

#define SCALE_Q 0.18033688011112042f   // 0.125 * log2(e), folded into Q at proj

__device__ __forceinline__ unsigned short f2bf(float f) {
    union { float f; unsigned int u; } v; v.f = f;
    unsigned int u = v.u;
    return (unsigned short)((u + 0x7fffu + ((u >> 16) & 1u)) >> 16);
}

__device__ __forceinline__ int cvtpk(float lo, float hi) {
    int r;
    asm("v_cvt_pk_bf16_f32 %0, %1, %2" : "=v"(r) : "v"(lo), "v"(hi));
    return r;
}

// ---------------------------------------------------------------------------
// Kernel 1: projection GEMM  C = X @ W^T, bf16 MFMA.  (unchanged, ~42 us)
//   z=0: qh[h][s][64] bf16, RoPE'd, PRE-SCALED by 0.125*log2(e)
//   z=1: kh[h][s][64] bf16, RoPE'd
//   z=2: vht[h][64][s] bf16 transposed
// ---------------------------------------------------------------------------
__global__ __launch_bounds__(256) void proj_rope_kernel(
    const float* __restrict__ Xq, const float* __restrict__ Xk, const float* __restrict__ Xv,
    const float* __restrict__ Wq, const float* __restrict__ Wk, const float* __restrict__ Wv,
    unsigned short* __restrict__ qh, unsigned short* __restrict__ kh,
    unsigned short* __restrict__ vht)
{
    const int tz = blockIdx.z;
    const float* __restrict__ X = (tz == 0) ? Xq : (tz == 1) ? Xk : Xv;
    const float* __restrict__ W = (tz == 0) ? Wq : (tz == 1) ? Wk : Wv;

    const int tid = threadIdx.x;
    const int lane = tid & 63;
    const int wid = tid >> 6;
    const int l15 = lane & 15;
    const int l4 = lane >> 4;
    const int wr = wid >> 1, wc = wid & 1;

    const int m0 = blockIdx.x * 128;
    const int n0 = blockIdx.y * 128;

    __shared__ __align__(16) unsigned short Ab[128 * 32];
    __shared__ __align__(16) unsigned short Bb[128 * 32];

    float4 ra[4], rb[4];
    f32x4 acc[4][4] = {};

    #pragma unroll
    for (int c = 0; c < 4; ++c) {
        int i = tid + (c << 8);
        int row = i >> 3;
        int c4 = (i & 7) << 2;
        ra[c] = *reinterpret_cast<const float4*>(X + (size_t)(m0 + row) * DMODEL + c4);
        rb[c] = *reinterpret_cast<const float4*>(W + (size_t)(n0 + row) * DMODEL + c4);
    }

    for (int kt = 0; kt < 32; ++kt) {
        if (kt > 0) __syncthreads();
        #pragma unroll
        for (int c = 0; c < 4; ++c) {
            int i = tid + (c << 8);
            int row = i >> 3;
            int c4 = (i & 7) << 2;
            int byte = row * 64 + (((c4 >> 3) ^ ((row >> 1) & 3)) << 4) + ((c4 << 1) & 15);
            uint2 pa, pb;
            pa.x = (unsigned)f2bf(ra[c].x) | ((unsigned)f2bf(ra[c].y) << 16);
            pa.y = (unsigned)f2bf(ra[c].z) | ((unsigned)f2bf(ra[c].w) << 16);
            pb.x = (unsigned)f2bf(rb[c].x) | ((unsigned)f2bf(rb[c].y) << 16);
            pb.y = (unsigned)f2bf(rb[c].z) | ((unsigned)f2bf(rb[c].w) << 16);
            *reinterpret_cast<uint2*>(reinterpret_cast<char*>(Ab) + byte) = pa;
            *reinterpret_cast<uint2*>(reinterpret_cast<char*>(Bb) + byte) = pb;
        }
        if (kt < 31) {
            int k0 = (kt + 1) << 5;
            #pragma unroll
            for (int c = 0; c < 4; ++c) {
                int i = tid + (c << 8);
                int row = i >> 3;
                int c4 = (i & 7) << 2;
                ra[c] = *reinterpret_cast<const float4*>(X + (size_t)(m0 + row) * DMODEL + k0 + c4);
                rb[c] = *reinterpret_cast<const float4*>(W + (size_t)(n0 + row) * DMODEL + k0 + c4);
            }
        }
        __syncthreads();

        v8bf af[4], bfr[4];
        #pragma unroll
        for (int mi = 0; mi < 4; ++mi) {
            int row = wr * 64 + mi * 16 + l15;
            int byte = row * 64 + ((l4 ^ ((row >> 1) & 3)) << 4);
            af[mi] = *reinterpret_cast<const v8bf*>(reinterpret_cast<const char*>(Ab) + byte);
        }
        #pragma unroll
        for (int ni = 0; ni < 4; ++ni) {
            int row = wc * 64 + ni * 16 + l15;
            int byte = row * 64 + ((l4 ^ ((row >> 1) & 3)) << 4);
            bfr[ni] = *reinterpret_cast<const v8bf*>(reinterpret_cast<const char*>(Bb) + byte);
        }
        #pragma unroll
        for (int mi = 0; mi < 4; ++mi)
            #pragma unroll
            for (int ni = 0; ni < 4; ++ni)
                acc[mi][ni] = __builtin_amdgcn_mfma_f32_16x16x32_bf16(af[mi], bfr[ni], acc[mi][ni], 0, 0, 0);
    }

    const int h = (n0 >> 6) + wc;
    const int mbase = m0 + wr * 64;
    if (tz == 2) {
        unsigned short* base = vht + (size_t)h * HDIM * SEQ;
        #pragma unroll
        for (int mi = 0; mi < 4; ++mi) {
            #pragma unroll
            for (int ni = 0; ni < 4; ++ni) {
                int d = ni * 16 + l15;
                int m = mbase + mi * 16 + l4 * 4;
                uint2 pk;
                pk.x = (unsigned)f2bf(acc[mi][ni][0]) | ((unsigned)f2bf(acc[mi][ni][1]) << 16);
                pk.y = (unsigned)f2bf(acc[mi][ni][2]) | ((unsigned)f2bf(acc[mi][ni][3]) << 16);
                *reinterpret_cast<uint2*>(base + (size_t)d * SEQ + m) = pk;
            }
        }
    } else {
        unsigned short* base = ((tz == 0) ? qh : kh) + (size_t)h * SEQ * HDIM;
        const float scl = (tz == 0) ? SCALE_Q : 1.0f;   // fold softmax scale into Q
        #pragma unroll
        for (int ni = 0; ni < 2; ++ni) {
            int j = ni * 16 + l15;
            float invf = expf(-(float)j * 0.28782313662425574f);  // ln(10000)/32
            #pragma unroll
            for (int mi = 0; mi < 4; ++mi) {
                #pragma unroll
                for (int r = 0; r < 4; ++r) {
                    int m = mbase + mi * 16 + l4 * 4 + r;
                    float ang = (float)m * invf;
                    float sn, cs;
                    sincosf(ang, &sn, &cs);
                    sn *= scl; cs *= scl;
                    float x1 = acc[mi][ni][r];
                    float x2 = acc[mi][ni + 2][r];
                    base[(size_t)m * HDIM + j]      = f2bf(x1 * cs - x2 * sn);
                    base[(size_t)m * HDIM + j + 32] = f2bf(x1 * sn + x2 * cs);
                }
            }
        }
    }
}

// ---------------------------------------------------------------------------
// Kernel 2: causal flash attention. 4 waves x 32 q-rows = 128-row block,
// swapped-QK^T 32x32 in-register softmax per wave; K/V shared via LDS.
// Per 64-kv round: K(64x64) + V^T(64x64) bf16 tiles reg-staged cooperatively
// (each wave 4 coalesced 1KB loads, issue-early/write-late, double-buffered,
// 1 barrier/round) into (row&7)-XOR-swizzled LDS; fragments via ds_read_b128.
// Complementary pairing per XCD: co-resident blocks sum to 66 rounds.
// ---------------------------------------------------------------------------
__global__ __launch_bounds__(256, 2) void attn_kernel(
    const unsigned short* __restrict__ qh, const unsigned short* __restrict__ kh,
    const unsigned short* __restrict__ vht, float* __restrict__ out)
{
    const int tid = threadIdx.x;
    const int lane = tid & 63;
    const int wid = tid >> 6;
    const int l31 = lane & 31;
    const int l5 = lane >> 5;
    const int r7 = l31 & 7;

    // block mapping: xcd = bid&7 owns heads {2x,2x+1}; complementary pairing:
    // j<32 -> head 2x, qb=31-j (64-2j rounds); j>=32 -> head 2x+1, qb=j-32
    // (2j+2 rounds). Blocks j and j+32 land on the same CU -> 66 rounds/CU.
    const int bid = blockIdx.x;
    const int xcd = bid & 7;
    const int j = bid >> 3;
    const int h = (xcd << 1) | (j >> 5);
    const int qb = (j < 32) ? (31 - j) : (j - 32);
    const int q0 = qb * 128;
    const int nt = 2 * qb + 2;
    const int qr0 = q0 + wid * 32;
    const int q = qr0 + l31;
    const int tmax = (qr0 + 31) >> 6;   // last kv-round this wave computes

    __shared__ __align__(16) unsigned char Kt[2][8192];
    __shared__ __align__(16) unsigned char Vt[2][8192];

    // Q B-fragments (pre-scaled at proj): col=q=l31, k=d=dk*16+l5*8+e
    v8bf qf[4];
    {
        const unsigned short* qbase = qh + ((size_t)h * SEQ + q) * HDIM + l5 * 8;
        #pragma unroll
        for (int dk = 0; dk < 4; ++dk)
            qf[dk] = *reinterpret_cast<const v8bf*>(qbase + dk * 16);
    }

    // staging assignment: waves 0,1 -> K segs {0..3}/{4..7}; waves 2,3 -> V.
    const bool isV = wid >= 2;
    const int wseg = (wid & 1) * 4;
    const int lsub = lane >> 3;
    const int swz16 = ((lane & 7) ^ (lsub & 7)) << 4;   // swizzled 16B-block
    const unsigned short* __restrict__ vrow0 = vht + ((size_t)h * 64 + wseg * 8 + lsub) * SEQ + (lane & 7) * 8;
    const unsigned char* __restrict__ kbase0 = reinterpret_cast<const unsigned char*>(
        kh + (size_t)h * SEQ * HDIM) + wseg * 1024 + lane * 16;

    auto STAGE_LOAD = [&](uint4 (&sr)[4], int T) {
        if (!isV) {
            const unsigned char* kb = kbase0 + (size_t)T * 8192;
            #pragma unroll
            for (int g = 0; g < 4; ++g)
                sr[g] = *reinterpret_cast<const uint4*>(kb + g * 1024);
        } else {
            const unsigned short* vb = vrow0 + T * 64;
            #pragma unroll
            for (int g = 0; g < 4; ++g)
                sr[g] = *reinterpret_cast<const uint4*>(vb + (size_t)g * 8 * SEQ);
        }
    };
    auto STAGE_WRITE = [&](uint4 (&sr)[4], int b) {
        unsigned char* base = (isV ? Vt[b] : Kt[b]) + wseg * 1024 + lsub * 128 + swz16;
        #pragma unroll
        for (int g = 0; g < 4; ++g)
            *reinterpret_cast<uint4*>(base + g * 1024) = sr[g];
    };

    f32x16 of[2] = {};
    float mreg = -INFINITY, lreg = 0.0f;

    uint4 sr[4];
    STAGE_LOAD(sr, 0);
    STAGE_WRITE(sr, 0);

    for (int t = 0; t < nt; ++t) {
        __syncthreads();                       // tile t ready in LDS
        const bool hn = (t + 1 < nt);
        if (hn) STAGE_LOAD(sr, t + 1);         // in flight during compute

        if (t <= tmax) {
            const unsigned char* Kc = Kt[t & 1];
            const unsigned char* Vc = Vt[t & 1];

            // ---- S^T = K Q^T : col=q=l31, kv = t*64+32ns+(i&3)+8*(i>>2)+4*l5
            f32x16 st[2];
            #pragma unroll
            for (int ns = 0; ns < 2; ++ns) {
                f32x16 acc = {};
                #pragma unroll
                for (int dk = 0; dk < 4; ++dk) {
                    v8bf kf = *reinterpret_cast<const v8bf*>(
                        Kc + (ns * 32 + l31) * 128 + (((dk * 2 + l5) ^ r7) << 4));
                    acc = __builtin_amdgcn_mfma_f32_32x32x16_bf16(kf, qf[dk], acc, 0, 0, 0);
                }
                st[ns] = acc;
            }

            // ---- causal mask: only the wave's diagonal round needs it
            if (t == tmax) {
                const int kvb = t * 64 + 4 * l5;
                #pragma unroll
                for (int ns = 0; ns < 2; ++ns)
                    #pragma unroll
                    for (int i = 0; i < 16; ++i) {
                        int kv = kvb + ns * 32 + (i & 3) + 8 * (i >> 2);
                        if (kv > q) st[ns][i] = -INFINITY;
                    }
            }

            // ---- row max: in-lane tree + 1 permlane32_swap
            float t16[16];
            #pragma unroll
            for (int i = 0; i < 16; ++i) t16[i] = fmaxf(st[0][i], st[1][i]);
            #pragma unroll
            for (int i = 0; i < 8; ++i) t16[i] = fmaxf(t16[i], t16[i + 8]);
            #pragma unroll
            for (int i = 0; i < 4; ++i) t16[i] = fmaxf(t16[i], t16[i + 4]);
            float pmax = fmaxf(fmaxf(t16[0], t16[1]), fmaxf(t16[2], t16[3]));
            {
                i32x2 sw = __builtin_amdgcn_permlane32_swap(__float_as_int(pmax), __float_as_int(pmax), false, false);
                pmax = fmaxf(__int_as_float(sw.x), __int_as_float(sw.y));
            }

            // ---- defer-max (T13)
            if (!__all(pmax - mreg <= 8.0f)) {
                float mnew = fmaxf(mreg, pmax);
                float sc = exp2f(mreg - mnew);
                lreg *= sc;
                #pragma unroll
                for (int dt = 0; dt < 2; ++dt)
                    #pragma unroll
                    for (int i = 0; i < 16; ++i) of[dt][i] *= sc;
                mreg = mnew;
            }

            // ---- exp2 + partial row-sum
            float ps0 = 0.f, ps1 = 0.f, ps2 = 0.f, ps3 = 0.f;
            #pragma unroll
            for (int ns = 0; ns < 2; ++ns)
                #pragma unroll
                for (int i = 0; i < 16; ++i) {
                    float p = exp2f(st[ns][i] - mreg);
                    st[ns][i] = p;
                    if ((i & 3) == 0) ps0 += p; else if ((i & 3) == 1) ps1 += p;
                    else if ((i & 3) == 2) ps2 += p; else ps3 += p;
                }
            lreg += (ps0 + ps1) + (ps2 + ps3);

            // ---- P^T B-fragments: cvt_pk + permlane32_swap (T12)
            v8bf pt[4];
            #pragma unroll
            for (int kb = 0; kb < 4; ++kb) {
                int ns = kb >> 1, kp = (kb & 1) * 8;
                int A0 = cvtpk(st[ns][kp + 0], st[ns][kp + 1]);
                int A1 = cvtpk(st[ns][kp + 2], st[ns][kp + 3]);
                int B0 = cvtpk(st[ns][kp + 4], st[ns][kp + 5]);
                int B1 = cvtpk(st[ns][kp + 6], st[ns][kp + 7]);
                i32x2 s0 = __builtin_amdgcn_permlane32_swap(A0, B0, false, false);
                i32x2 s1 = __builtin_amdgcn_permlane32_swap(A1, B1, false, false);
                i32x4 u; u.x = s0.x; u.y = s1.x; u.z = s0.y; u.w = s1.y;
                v8bf p; __builtin_memcpy(&p, &u, 16);
                pt[kb] = p;
            }

            // ---- O^T += V^T P^T
            #pragma unroll
            for (int dt = 0; dt < 2; ++dt)
                #pragma unroll
                for (int kb = 0; kb < 4; ++kb) {
                    v8bf vf = *reinterpret_cast<const v8bf*>(
                        Vc + (dt * 32 + l31) * 128 + (((kb * 2 + l5) ^ r7) << 4));
                    of[dt] = __builtin_amdgcn_mfma_f32_32x32x16_bf16(vf, pt[kb], of[dt], 0, 0, 0);
                }
        }

        if (hn) STAGE_WRITE(sr, (t + 1) & 1);  // vmcnt wait lands here, post-compute
    }

    // ---- finalize: pair-sum l across halves, divide, store float4
    {
        i32x2 sw = __builtin_amdgcn_permlane32_swap(__float_as_int(lreg), __float_as_int(lreg), false, false);
        lreg = __int_as_float(sw.x) + __int_as_float(sw.y);
    }
    float inv = 1.0f / lreg;
    float* obase = out + (size_t)q * DMODEL + h * HDIM + l5 * 4;
    #pragma unroll
    for (int dt = 0; dt < 2; ++dt)
        #pragma unroll
        for (int g = 0; g < 4; ++g) {
            f32x4 o4;
            o4[0] = of[dt][g * 4 + 0] * inv;
            o4[1] = of[dt][g * 4 + 1] * inv;
            o4[2] = of[dt][g * 4 + 2] * inv;
            o4[3] = of[dt][g * 4 + 3] * inv;
            *reinterpret_cast<f32x4*>(obase + dt * 32 + g * 8) = o4;
        }
}

extern "C" void kernel_launch(void* const* d_in, const int* in_sizes, int n_in,
                              void* d_out, int out_size, void* d_ws, size_t ws_size,
                              hipStream_t stream) {
    (void)in_sizes; (void)n_in; (void)out_size; (void)ws_size;
    const float* q  = (const float*)d_in[0];
    const float* k  = (const float*)d_in[1];
    const float* v  = (const float*)d_in[2];
    // d_in[3] = mask: tril(ones) -> causal, applied analytically
    const float* Wq = (const float*)d_in[4];
    const float* Wk = (const float*)d_in[5];
    const float* Wv = (const float*)d_in[6];

    unsigned short* qh  = (unsigned short*)d_ws;                      // 8.4 MB
    unsigned short* kh  = qh + (size_t)NHEADS * SEQ * HDIM;           // 8.4 MB
    unsigned short* vht = kh + (size_t)NHEADS * SEQ * HDIM;           // 8.4 MB
    float* out = (float*)d_out;

    dim3 g1(SEQ / 128, DMODEL / 128, 3);
    proj_rope_kernel<<<g1, 256, 0, stream>>>(q, k, v, Wq, Wk, Wv, qh, kh, vht);

    attn_kernel<<<dim3(512), 256, 0, stream>>>(qh, kh, vht, out);
}

// Round 6
// 163.036 us; speedup vs baseline: 2.4822x; 1.3401x over previous
//
#include <hip/hip_runtime.h>
#include <math.h>

#define SEQ 4096
#define DMODEL 1024
#define NHEADS 16
#define HDIM 64

typedef __bf16 v8bf __attribute__((ext_vector_type(8)));
typedef float f32x4 __attribute__((ext_vector_type(4)));
typedef float f32x16 __attribute__((ext_vector_type(16)));
typedef int i32x2 __attribute__((ext_vector_type(2)));
typedef int i32x4 __attribute__((ext_vector_type(4)));

#define NPART 4608   // partial chunks (qb>=32): 16 heads * 288
#define SCALE_Q 0.18033688011112042f   // 0.125 * log2(e), folded into Q at proj

__device__ __forceinline__ unsigned short f2bf(float f) {
    union { float f; unsigned int u; } v; v.f = f;
    unsigned int u = v.u;
    return (unsigned short)((u + 0x7fffu + ((u >> 16) & 1u)) >> 16);
}

__device__ __forceinline__ int cvtpk(float lo, float hi) {
    int r;
    asm("v_cvt_pk_bf16_f32 %0, %1, %2" : "=v"(r) : "v"(lo), "v"(hi));
    return r;
}

// ---------------------------------------------------------------------------
// Kernel 1: projection GEMM  C = X @ W^T, bf16 MFMA.  (unchanged, ~42 us)
//   z=0: qh[h][s][64] bf16, RoPE'd, PRE-SCALED by 0.125*log2(e)
//   z=1: kh[h][s][64] bf16, RoPE'd
//   z=2: vht[h][64][s] bf16 transposed
// ---------------------------------------------------------------------------
__global__ __launch_bounds__(256) void proj_rope_kernel(
    const float* __restrict__ Xq, const float* __restrict__ Xk, const float* __restrict__ Xv,
    const float* __restrict__ Wq, const float* __restrict__ Wk, const float* __restrict__ Wv,
    unsigned short* __restrict__ qh, unsigned short* __restrict__ kh,
    unsigned short* __restrict__ vht)
{
    const int tz = blockIdx.z;
    const float* __restrict__ X = (tz == 0) ? Xq : (tz == 1) ? Xk : Xv;
    const float* __restrict__ W = (tz == 0) ? Wq : (tz == 1) ? Wk : Wv;

    const int tid = threadIdx.x;
    const int lane = tid & 63;
    const int wid = tid >> 6;
    const int l15 = lane & 15;
    const int l4 = lane >> 4;
    const int wr = wid >> 1, wc = wid & 1;

    const int m0 = blockIdx.x * 128;
    const int n0 = blockIdx.y * 128;

    __shared__ __align__(16) unsigned short Ab[128 * 32];
    __shared__ __align__(16) unsigned short Bb[128 * 32];

    float4 ra[4], rb[4];
    f32x4 acc[4][4] = {};

    #pragma unroll
    for (int c = 0; c < 4; ++c) {
        int i = tid + (c << 8);
        int row = i >> 3;
        int c4 = (i & 7) << 2;
        ra[c] = *reinterpret_cast<const float4*>(X + (size_t)(m0 + row) * DMODEL + c4);
        rb[c] = *reinterpret_cast<const float4*>(W + (size_t)(n0 + row) * DMODEL + c4);
    }

    for (int kt = 0; kt < 32; ++kt) {
        if (kt > 0) __syncthreads();
        #pragma unroll
        for (int c = 0; c < 4; ++c) {
            int i = tid + (c << 8);
            int row = i >> 3;
            int c4 = (i & 7) << 2;
            int byte = row * 64 + (((c4 >> 3) ^ ((row >> 1) & 3)) << 4) + ((c4 << 1) & 15);
            uint2 pa, pb;
            pa.x = (unsigned)f2bf(ra[c].x) | ((unsigned)f2bf(ra[c].y) << 16);
            pa.y = (unsigned)f2bf(ra[c].z) | ((unsigned)f2bf(ra[c].w) << 16);
            pb.x = (unsigned)f2bf(rb[c].x) | ((unsigned)f2bf(rb[c].y) << 16);
            pb.y = (unsigned)f2bf(rb[c].z) | ((unsigned)f2bf(rb[c].w) << 16);
            *reinterpret_cast<uint2*>(reinterpret_cast<char*>(Ab) + byte) = pa;
            *reinterpret_cast<uint2*>(reinterpret_cast<char*>(Bb) + byte) = pb;
        }
        if (kt < 31) {
            int k0 = (kt + 1) << 5;
            #pragma unroll
            for (int c = 0; c < 4; ++c) {
                int i = tid + (c << 8);
                int row = i >> 3;
                int c4 = (i & 7) << 2;
                ra[c] = *reinterpret_cast<const float4*>(X + (size_t)(m0 + row) * DMODEL + k0 + c4);
                rb[c] = *reinterpret_cast<const float4*>(W + (size_t)(n0 + row) * DMODEL + k0 + c4);
            }
        }
        __syncthreads();

        v8bf af[4], bfr[4];
        #pragma unroll
        for (int mi = 0; mi < 4; ++mi) {
            int row = wr * 64 + mi * 16 + l15;
            int byte = row * 64 + ((l4 ^ ((row >> 1) & 3)) << 4);
            af[mi] = *reinterpret_cast<const v8bf*>(reinterpret_cast<const char*>(Ab) + byte);
        }
        #pragma unroll
        for (int ni = 0; ni < 4; ++ni) {
            int row = wc * 64 + ni * 16 + l15;
            int byte = row * 64 + ((l4 ^ ((row >> 1) & 3)) << 4);
            bfr[ni] = *reinterpret_cast<const v8bf*>(reinterpret_cast<const char*>(Bb) + byte);
        }
        #pragma unroll
        for (int mi = 0; mi < 4; ++mi)
            #pragma unroll
            for (int ni = 0; ni < 4; ++ni)
                acc[mi][ni] = __builtin_amdgcn_mfma_f32_16x16x32_bf16(af[mi], bfr[ni], acc[mi][ni], 0, 0, 0);
    }

    const int h = (n0 >> 6) + wc;
    const int mbase = m0 + wr * 64;
    if (tz == 2) {
        unsigned short* base = vht + (size_t)h * HDIM * SEQ;
        #pragma unroll
        for (int mi = 0; mi < 4; ++mi) {
            #pragma unroll
            for (int ni = 0; ni < 4; ++ni) {
                int d = ni * 16 + l15;
                int m = mbase + mi * 16 + l4 * 4;
                uint2 pk;
                pk.x = (unsigned)f2bf(acc[mi][ni][0]) | ((unsigned)f2bf(acc[mi][ni][1]) << 16);
                pk.y = (unsigned)f2bf(acc[mi][ni][2]) | ((unsigned)f2bf(acc[mi][ni][3]) << 16);
                *reinterpret_cast<uint2*>(base + (size_t)d * SEQ + m) = pk;
            }
        }
    } else {
        unsigned short* base = ((tz == 0) ? qh : kh) + (size_t)h * SEQ * HDIM;
        const float scl = (tz == 0) ? SCALE_Q : 1.0f;   // fold softmax scale into Q
        #pragma unroll
        for (int ni = 0; ni < 2; ++ni) {
            int j = ni * 16 + l15;
            float invf = expf(-(float)j * 0.28782313662425574f);  // ln(10000)/32
            #pragma unroll
            for (int mi = 0; mi < 4; ++mi) {
                #pragma unroll
                for (int r = 0; r < 4; ++r) {
                    int m = mbase + mi * 16 + l4 * 4 + r;
                    float ang = (float)m * invf;
                    float sn, cs;
                    sincosf(ang, &sn, &cs);
                    sn *= scl; cs *= scl;
                    float x1 = acc[mi][ni][r];
                    float x2 = acc[mi][ni + 2][r];
                    base[(size_t)m * HDIM + j]      = f2bf(x1 * cs - x2 * sn);
                    base[(size_t)m * HDIM + j + 32] = f2bf(x1 * sn + x2 * cs);
                }
            }
        }
    }
}

// ---------------------------------------------------------------------------
// Kernel 2: repack K and V into MFMA-fragment order (one-shot gather).
//   kfr[h][T][ns*4+dk][lane][8] : lane holds K[T*64+ns*32+l31][dk*16+l5*8+j]
//   vfr[h][T][dt*4+kb][lane][8] : lane holds V^T[dt*32+l31][T*64+kb*16+l5*8+j]
// In attention every fragment load becomes base+lane*16B = dense 1KB.
// 256 blocks x 4 waves; wave = one (h, T) tile pair of K and V.
// ---------------------------------------------------------------------------
__global__ __launch_bounds__(256) void repack_kernel(
    const unsigned short* __restrict__ kh, const unsigned short* __restrict__ vht,
    unsigned short* __restrict__ kfr, unsigned short* __restrict__ vfr)
{
    const int lane = threadIdx.x & 63;
    const int wid = threadIdx.x >> 6;
    const int l31 = lane & 31;
    const int l5 = lane >> 5;
    const int h = blockIdx.x >> 4;
    const int T = ((blockIdx.x & 15) << 2) + wid;

    const unsigned short* __restrict__ ksrc = kh + ((size_t)h * SEQ + T * 64) * HDIM;
    unsigned short* __restrict__ kdst = kfr + ((size_t)(h * 64 + T)) * 4096 + lane * 8;
    #pragma unroll
    for (int ns = 0; ns < 2; ++ns)
        #pragma unroll
        for (int dk = 0; dk < 4; ++dk) {
            v8bf f = *reinterpret_cast<const v8bf*>(ksrc + (ns * 32 + l31) * HDIM + dk * 16 + l5 * 8);
            *reinterpret_cast<v8bf*>(kdst + (ns * 4 + dk) * 512) = f;
        }

    const unsigned short* __restrict__ vsrc = vht + ((size_t)h * 64) * SEQ;
    unsigned short* __restrict__ vdst = vfr + ((size_t)(h * 64 + T)) * 4096 + lane * 8;
    #pragma unroll
    for (int dt = 0; dt < 2; ++dt)
        #pragma unroll
        for (int kb = 0; kb < 4; ++kb) {
            v8bf f = *reinterpret_cast<const v8bf*>(
                vsrc + (size_t)(dt * 32 + l31) * SEQ + T * 64 + kb * 16 + l5 * 8);
            *reinterpret_cast<v8bf*>(vdst + (dt * 4 + kb) * 512) = f;
        }
}

// ---------------------------------------------------------------------------
// Kernel 3: causal flash attention, swapped-QK^T 32x32, flash-decoding split.
// 1 wave/block, 32 q-rows, KV chunk of <=16 rounds (1024 kv) per wave.
// 5120 balanced waves, no LDS, no barriers. K/V fragment loads are DENSE
// (pre-fragmented kfr/vfr): base + lane*16B, one 1KB instr per fragment.
// setprio(1) around MFMA clusters (T5). XCD-grouped heads, long chunks first.
// qb<32: write out directly. qb>=32: bf16 partials + (m,l) -> combine.
// ---------------------------------------------------------------------------
__global__ __launch_bounds__(64, 2) void attn_kernel(
    const unsigned short* __restrict__ qh, const unsigned short* __restrict__ kfr,
    const unsigned short* __restrict__ vfr, float* __restrict__ out,
    unsigned short* __restrict__ po, float* __restrict__ ml)
{
    const int lane = threadIdx.x & 63;
    const int l31 = lane & 31;
    const int l5 = lane >> 5;

    const int bid = blockIdx.x;
    const int xcd = bid & 7;                 // HW: consecutive bids round-robin XCDs
    const int idx = bid >> 3;                // 0..639 per XCD
    const int hsel = (idx >= 320) ? 1 : 0;
    const int h = (xcd << 1) | hsel;         // 2 heads per XCD -> K/V L2-resident
    const int r = 319 - (idx - hsel * 320);  // descending: long chunks first

    int qb, c, nc;
    if (r < 32)       { qb = r;                     c = 0;            nc = 1; }
    else if (r < 96)  { qb = 32 + ((r - 32) >> 1);  c = (r - 32) & 1; nc = 2; }
    else if (r < 192) { int rr = r - 96; qb = 64 + rr / 3; c = rr - (qb - 64) * 3; nc = 3; }
    else              { int rr = r - 192; qb = 96 + (rr >> 2); c = rr & 3; nc = 4; }

    const int q0 = qb * 32;
    const int q = q0 + l31;
    const int nt = (q0 + 32 + 63) >> 6;      // total kv-rounds for this q-tile
    const int t0 = c * 16;
    const int t1 = min(t0 + 16, nt);

    const unsigned short* __restrict__ qbase = qh + ((size_t)h * SEQ + q) * HDIM + l5 * 8;
    const unsigned short* __restrict__ kfh = kfr + (size_t)h * 262144 + lane * 8;
    const unsigned short* __restrict__ vfh = vfr + (size_t)h * 262144 + lane * 8;

    v8bf qf[4];
    #pragma unroll
    for (int dk = 0; dk < 4; ++dk)
        qf[dk] = *reinterpret_cast<const v8bf*>(qbase + dk * 16);

    f32x16 of[2] = {};
    float mreg = -INFINITY, lreg = 0.0f;

    auto LOADK = [&](v8bf (&KB)[8], int T) {
        const unsigned short* kp = kfh + (size_t)T * 4096;
        #pragma unroll
        for (int f = 0; f < 8; ++f)
            KB[f] = *reinterpret_cast<const v8bf*>(kp + f * 512);
    };

    auto ROUND = [&](int T, v8bf (&KC)[8], v8bf (&KN)[8]) {
        // V^T fragments (dense 1KB loads; issued early, consumed after softmax)
        v8bf vf[8];
        {
            const unsigned short* vp = vfh + (size_t)T * 4096;
            #pragma unroll
            for (int f = 0; f < 8; ++f)
                vf[f] = *reinterpret_cast<const v8bf*>(vp + f * 512);
        }
        if (T + 1 < t1) LOADK(KN, T + 1);

        // S^T = K Q^T : col=q=l31, row_kv = T*64 + 32ns + (i&3)+8*(i>>2)+4*l5
        f32x16 st[2];
        __builtin_amdgcn_s_setprio(1);
        #pragma unroll
        for (int ns = 0; ns < 2; ++ns) {
            f32x16 acc = {};
            #pragma unroll
            for (int dk = 0; dk < 4; ++dk)
                acc = __builtin_amdgcn_mfma_f32_32x32x16_bf16(KC[ns * 4 + dk], qf[dk], acc, 0, 0, 0);
            st[ns] = acc;
        }
        __builtin_amdgcn_s_setprio(0);

        // causal mask: provably needed only on the globally-last round
        if (T == nt - 1) {
            const int kvb = T * 64 + 4 * l5;
            #pragma unroll
            for (int ns = 0; ns < 2; ++ns)
                #pragma unroll
                for (int i = 0; i < 16; ++i) {
                    int kv = kvb + ns * 32 + (i & 3) + 8 * (i >> 2);
                    if (kv > q) st[ns][i] = -INFINITY;
                }
        }

        // row max: in-lane tree + 1 permlane32_swap
        float t16[16];
        #pragma unroll
        for (int i = 0; i < 16; ++i) t16[i] = fmaxf(st[0][i], st[1][i]);
        #pragma unroll
        for (int i = 0; i < 8; ++i) t16[i] = fmaxf(t16[i], t16[i + 8]);
        #pragma unroll
        for (int i = 0; i < 4; ++i) t16[i] = fmaxf(t16[i], t16[i + 4]);
        float pmax = fmaxf(fmaxf(t16[0], t16[1]), fmaxf(t16[2], t16[3]));
        {
            i32x2 sw = __builtin_amdgcn_permlane32_swap(__float_as_int(pmax), __float_as_int(pmax), false, false);
            pmax = fmaxf(__int_as_float(sw.x), __int_as_float(sw.y));
        }

        // defer-max (T13): rescale only if max grew by > 8 (exp2 domain)
        if (!__all(pmax - mreg <= 8.0f)) {
            float mnew = fmaxf(mreg, pmax);
            float sc = exp2f(mreg - mnew);
            lreg *= sc;
            #pragma unroll
            for (int dt = 0; dt < 2; ++dt)
                #pragma unroll
                for (int i = 0; i < 16; ++i) of[dt][i] *= sc;
            mreg = mnew;
        }

        // exp2 + partial row-sum
        float ps0 = 0.f, ps1 = 0.f, ps2 = 0.f, ps3 = 0.f;
        #pragma unroll
        for (int ns = 0; ns < 2; ++ns)
            #pragma unroll
            for (int i = 0; i < 16; ++i) {
                float p = exp2f(st[ns][i] - mreg);
                st[ns][i] = p;
                if ((i & 3) == 0) ps0 += p; else if ((i & 3) == 1) ps1 += p;
                else if ((i & 3) == 2) ps2 += p; else ps3 += p;
            }
        lreg += (ps0 + ps1) + (ps2 + ps3);

        // P^T B-fragments: cvt_pk + permlane32_swap (T12)
        v8bf pt[4];
        #pragma unroll
        for (int kb = 0; kb < 4; ++kb) {
            int ns = kb >> 1, kp = (kb & 1) * 8;
            int A0 = cvtpk(st[ns][kp + 0], st[ns][kp + 1]);
            int A1 = cvtpk(st[ns][kp + 2], st[ns][kp + 3]);
            int B0 = cvtpk(st[ns][kp + 4], st[ns][kp + 5]);
            int B1 = cvtpk(st[ns][kp + 6], st[ns][kp + 7]);
            i32x2 s0 = __builtin_amdgcn_permlane32_swap(A0, B0, false, false);
            i32x2 s1 = __builtin_amdgcn_permlane32_swap(A1, B1, false, false);
            i32x4 u; u.x = s0.x; u.y = s1.x; u.z = s0.y; u.w = s1.y;
            v8bf p; __builtin_memcpy(&p, &u, 16);
            pt[kb] = p;
        }

        // O^T += V^T P^T
        __builtin_amdgcn_s_setprio(1);
        #pragma unroll
        for (int dt = 0; dt < 2; ++dt)
            #pragma unroll
            for (int kb = 0; kb < 4; ++kb)
                of[dt] = __builtin_amdgcn_mfma_f32_32x32x16_bf16(vf[dt * 4 + kb], pt[kb], of[dt], 0, 0, 0);
        __builtin_amdgcn_s_setprio(0);
    };

    v8bf kA[8], kB[8];
    LOADK(kA, t0);
    int t = t0;
    while (true) {
        ROUND(t, kA, kB);
        if (++t == t1) break;
        ROUND(t, kB, kA);
        if (++t == t1) break;
    }

    // pair-sum l across halves (both halves end with full row-sum)
    {
        i32x2 sw = __builtin_amdgcn_permlane32_swap(__float_as_int(lreg), __float_as_int(lreg), false, false);
        lreg = __int_as_float(sw.x) + __int_as_float(sw.y);
    }

    if (nc == 1) {
        float inv = 1.0f / lreg;
        float* obase = out + (size_t)q * DMODEL + h * HDIM + l5 * 4;
        #pragma unroll
        for (int dt = 0; dt < 2; ++dt)
            #pragma unroll
            for (int g = 0; g < 4; ++g) {
                f32x4 o4;
                o4[0] = of[dt][g * 4 + 0] * inv;
                o4[1] = of[dt][g * 4 + 1] * inv;
                o4[2] = of[dt][g * 4 + 2] * inv;
                o4[3] = of[dt][g * 4 + 3] * inv;
                *reinterpret_cast<f32x4*>(obase + dt * 32 + g * 8) = o4;
            }
    } else {
        const int p = h * 288 + (r - 32);
        unsigned short* pb = po + ((size_t)p * 32 + l31) * 64 + l5 * 4;
        #pragma unroll
        for (int dt = 0; dt < 2; ++dt)
            #pragma unroll
            for (int g = 0; g < 4; ++g) {
                uint2 u;
                u.x = (unsigned)cvtpk(of[dt][g * 4 + 0], of[dt][g * 4 + 1]);
                u.y = (unsigned)cvtpk(of[dt][g * 4 + 2], of[dt][g * 4 + 3]);
                *reinterpret_cast<uint2*>(pb + dt * 32 + g * 8) = u;
            }
        if (l5 == 0) {
            float2 v; v.x = mreg; v.y = lreg;
            reinterpret_cast<float2*>(ml)[(size_t)p * 32 + l31] = v;
        }
    }
}

// ---------------------------------------------------------------------------
// Kernel 4: combine partials for qb>=32 (2..4 chunks per q-tile).
// 1536 blocks x 256 threads (4 rows in parallel; was 64 thr -> 1.5 waves/CU).
// ---------------------------------------------------------------------------
__global__ __launch_bounds__(256) void combine_kernel(
    const unsigned short* __restrict__ po, const float* __restrict__ ml,
    float* __restrict__ out)
{
    const int b = blockIdx.x;
    const int h = b / 96;
    const int j = b - h * 96;
    const int qb = 32 + j;
    int nc, r0;
    if (qb < 64)      { nc = 2; r0 = 32 + ((qb - 32) << 1); }
    else if (qb < 96) { nc = 3; r0 = 96 + (qb - 64) * 3; }
    else              { nc = 4; r0 = 192 + ((qb - 96) << 2); }
    const int p0 = h * 288 + (r0 - 32);
    const int d = threadIdx.x & 63;
    const int rg = threadIdx.x >> 6;
    const int q0 = qb * 32;

    for (int row = rg; row < 32; row += 4) {
        float mc[4], lc[4];
        float M = -INFINITY;
        #pragma unroll
        for (int ci = 0; ci < 4; ++ci)
            if (ci < nc) {
                float2 v = reinterpret_cast<const float2*>(ml)[(size_t)(p0 + ci) * 32 + row];
                mc[ci] = v.x; lc[ci] = v.y;
                M = fmaxf(M, v.x);
            }
        float L = 0.0f, O = 0.0f;
        #pragma unroll
        for (int ci = 0; ci < 4; ++ci)
            if (ci < nc) {
                float w = exp2f(mc[ci] - M);
                L += lc[ci] * w;
                unsigned int raw = po[((size_t)(p0 + ci) * 32 + row) * 64 + d];
                union { unsigned int u; float f; } cv; cv.u = raw << 16;
                O += cv.f * w;
            }
        out[(size_t)(q0 + row) * DMODEL + h * HDIM + d] = O / L;
    }
}

extern "C" void kernel_launch(void* const* d_in, const int* in_sizes, int n_in,
                              void* d_out, int out_size, void* d_ws, size_t ws_size,
                              hipStream_t stream) {
    (void)in_sizes; (void)n_in; (void)out_size; (void)ws_size;
    const float* q  = (const float*)d_in[0];
    const float* k  = (const float*)d_in[1];
    const float* v  = (const float*)d_in[2];
    // d_in[3] = mask: tril(ones) -> causal, applied analytically
    const float* Wq = (const float*)d_in[4];
    const float* Wk = (const float*)d_in[5];
    const float* Wv = (const float*)d_in[6];

    // ws layout (po overlays kh+vht, which are dead after repack):
    // qh | kfr | vfr | kh | vht ...  po=kh_base (18.9MB) | ml   -> ~45.3 MB
    unsigned short* qh  = (unsigned short*)d_ws;                      // 8.4 MB
    unsigned short* kfr = qh  + (size_t)NHEADS * SEQ * HDIM;          // 8.4 MB
    unsigned short* vfr = kfr + (size_t)NHEADS * SEQ * HDIM;          // 8.4 MB
    unsigned short* kh  = vfr + (size_t)NHEADS * SEQ * HDIM;          // 8.4 MB
    unsigned short* vht = kh  + (size_t)NHEADS * SEQ * HDIM;          // 8.4 MB
    unsigned short* po  = kh;                                         // 18.9 MB (overlay)
    float* ml = (float*)(po + (size_t)NPART * 32 * 64);               // 1.2 MB
    float* out = (float*)d_out;

    dim3 g1(SEQ / 128, DMODEL / 128, 3);
    proj_rope_kernel<<<g1, 256, 0, stream>>>(q, k, v, Wq, Wk, Wv, qh, kh, vht);

    repack_kernel<<<dim3(256), 256, 0, stream>>>(kh, vht, kfr, vfr);

    attn_kernel<<<dim3(16 * 320), 64, 0, stream>>>(qh, kfr, vfr, out, po, ml);

    combine_kernel<<<dim3(16 * 96), 256, 0, stream>>>(po, ml, out);
}